// Round 1
// baseline (2274.800 us; speedup 1.0000x reference)
//
#include <hip/hip_runtime.h>
#include <stdint.h>

// Problem constants (from reference)
#define TT 8192          // time length
#define CC 72            // channels
#define PP 7             // patch size
#define NN (TT - PP + 1) // 8186 patches
#define DD (CC * PP)     // 504 patch dim
#define TI 64
#define TJ 64
constexpr float INV_D = 1.0f / (float)DD;
constexpr float ALPHA_C = 0.01f;

// ------------------------------------------------------------------
// prep: patch norms sx/sy; init colmin (+inf bits), packed (~0), dsum
// ------------------------------------------------------------------
__global__ void prep_kernel(const float* __restrict__ X, const float* __restrict__ Y,
                            float* __restrict__ sx, float* __restrict__ sy,
                            unsigned* __restrict__ colmin,
                            unsigned long long* __restrict__ packed,
                            float* __restrict__ dsum) {
    int i = blockIdx.x * 256 + threadIdx.x;
    if (i == 0) *dsum = 0.0f;
    if (i < TT) { colmin[i] = 0x7f800000u; packed[i] = ~0ULL; }
    if (i < NN) {
        float ax = 0.0f, ay = 0.0f;
        for (int c = 0; c < CC; ++c) {
            const float* xr = X + c * TT + i;
            const float* yr = Y + c * TT + i;
#pragma unroll
            for (int k = 0; k < PP; ++k) {
                float v = xr[k]; ax += v * v;
                float w = yr[k]; ay += w * w;
            }
        }
        sx[i] = ax; sy[i] = ay;
    }
}

// ------------------------------------------------------------------
// pass1: column minima of dist  (64x64 tiles, 4x4 per thread)
// ------------------------------------------------------------------
__global__ __launch_bounds__(256) void pass1_kernel(
        const float* __restrict__ X, const float* __restrict__ Y,
        const float* __restrict__ sx, const float* __restrict__ sy,
        unsigned* __restrict__ colmin) {
    __shared__ float Xs[CC][TI + PP - 1];   // [72][70]
    __shared__ float Ys[CC][TJ + PP - 1];
    __shared__ unsigned cmin_s[TJ];

    const int i0 = blockIdx.y * TI;
    const int j0 = blockIdx.x * TJ;
    const int tid = threadIdx.x;

    for (int idx = tid; idx < CC * (TI + PP - 1); idx += 256) {
        int c = idx / (TI + PP - 1);
        int t = idx - c * (TI + PP - 1);
        Xs[c][t] = X[c * TT + min(i0 + t, TT - 1)];
        Ys[c][t] = Y[c * TT + min(j0 + t, TT - 1)];
    }
    if (tid < TJ) cmin_s[tid] = 0x7f800000u;
    __syncthreads();

    const int tx = tid & 15, ty = tid >> 4;
    const int ri = ty * 4, rj = tx * 4;

    float acc[4][4] = {};
    for (int c = 0; c < CC; ++c) {
        float xv[10], yv[10];
#pragma unroll
        for (int m = 0; m < 10; ++m) { xv[m] = Xs[c][ri + m]; yv[m] = Ys[c][rj + m]; }
#pragma unroll
        for (int k = 0; k < PP; ++k)
#pragma unroll
            for (int a = 0; a < 4; ++a)
#pragma unroll
                for (int b = 0; b < 4; ++b)
                    acc[a][b] += xv[a + k] * yv[b + k];
    }

#pragma unroll
    for (int b = 0; b < 4; ++b) {
        int j = j0 + rj + b;
        if (j >= NN) continue;
        float m = __uint_as_float(0x7f800000u);
        float syj = sy[j];
#pragma unroll
        for (int a = 0; a < 4; ++a) {
            int i = i0 + ri + a;
            if (i < NN) {
                float d = (sx[i] + syj - 2.0f * acc[a][b]) * INV_D;
                m = fminf(m, d);
            }
        }
        atomicMin(&cmin_s[rj + b], __float_as_uint(m));  // nonneg floats: bit order == value order
    }
    __syncthreads();
    if (tid < TJ) {
        int j = j0 + tid;
        if (j < NN) atomicMin(&colmin[j], cmin_s[tid]);
    }
}

// ------------------------------------------------------------------
// pass2: row argmin of dist/(alpha+colmin[j]), packed (bits<<32)|j
// ------------------------------------------------------------------
__global__ __launch_bounds__(256) void pass2_kernel(
        const float* __restrict__ X, const float* __restrict__ Y,
        const float* __restrict__ sx, const float* __restrict__ sy,
        const unsigned* __restrict__ colmin,
        unsigned long long* __restrict__ packed) {
    __shared__ float Xs[CC][TI + PP - 1];
    __shared__ float Ys[CC][TJ + PP - 1];
    __shared__ unsigned long long pmin_s[TI];

    const int i0 = blockIdx.y * TI;
    const int j0 = blockIdx.x * TJ;
    const int tid = threadIdx.x;

    for (int idx = tid; idx < CC * (TI + PP - 1); idx += 256) {
        int c = idx / (TI + PP - 1);
        int t = idx - c * (TI + PP - 1);
        Xs[c][t] = X[c * TT + min(i0 + t, TT - 1)];
        Ys[c][t] = Y[c * TT + min(j0 + t, TT - 1)];
    }
    if (tid < TI) pmin_s[tid] = ~0ULL;
    __syncthreads();

    const int tx = tid & 15, ty = tid >> 4;
    const int ri = ty * 4, rj = tx * 4;

    float acc[4][4] = {};
    for (int c = 0; c < CC; ++c) {
        float xv[10], yv[10];
#pragma unroll
        for (int m = 0; m < 10; ++m) { xv[m] = Xs[c][ri + m]; yv[m] = Ys[c][rj + m]; }
#pragma unroll
        for (int k = 0; k < PP; ++k)
#pragma unroll
            for (int a = 0; a < 4; ++a)
#pragma unroll
                for (int b = 0; b < 4; ++b)
                    acc[a][b] += xv[a + k] * yv[b + k];
    }

    float acm[4];
#pragma unroll
    for (int b = 0; b < 4; ++b) {
        int j = j0 + rj + b;
        acm[b] = (j < NN) ? (ALPHA_C + __uint_as_float(colmin[j])) : 1.0f;
    }

#pragma unroll
    for (int a = 0; a < 4; ++a) {
        int i = i0 + ri + a;
        if (i >= NN) continue;
        float sxi = sx[i];
        unsigned long long best = ~0ULL;
#pragma unroll
        for (int b = 0; b < 4; ++b) {
            int j = j0 + rj + b;
            if (j < NN) {
                float d  = (sxi + sy[j] - 2.0f * acc[a][b]) * INV_D;
                float nd = d / acm[b];   // matches reference's division
                unsigned long long pk =
                    ((unsigned long long)__float_as_uint(nd) << 32) | (unsigned)j;
                best = (pk < best) ? pk : best;
            }
        }
        atomicMin(&pmin_s[ri + a], best);
    }
    __syncthreads();
    if (tid < TI) {
        int i = i0 + tid;
        if (i < NN) atomicMin(&packed[i], pmin_s[tid]);
    }
}

// ------------------------------------------------------------------
// finalize: nnf[i], dists[i] recompute, sum for mean
// ------------------------------------------------------------------
__global__ void finalize_kernel(const float* __restrict__ X, const float* __restrict__ Y,
                                const float* __restrict__ sx, const float* __restrict__ sy,
                                const unsigned long long* __restrict__ packed,
                                int* __restrict__ nnf, float* __restrict__ dsum) {
    int i = blockIdx.x * 256 + threadIdx.x;
    float dval = 0.0f;
    if (i < NN) {
        int j = (int)(packed[i] & 0xffffffffu);
        nnf[i] = j;
        float dot = 0.0f;
        for (int c = 0; c < CC; ++c) {
            const float* xr = X + c * TT + i;
            const float* yr = Y + c * TT + j;
#pragma unroll
            for (int k = 0; k < PP; ++k) dot += xr[k] * yr[k];
        }
        dval = (sx[i] + sy[j] - 2.0f * dot) * INV_D;
    }
    __shared__ float red[256];
    red[threadIdx.x] = dval;
    __syncthreads();
    for (int s = 128; s > 0; s >>= 1) {
        if (threadIdx.x < s) red[threadIdx.x] += red[threadIdx.x + s];
        __syncthreads();
    }
    if (threadIdx.x == 0) atomicAdd(dsum, red[0]);
}

// ------------------------------------------------------------------
// fold: gather-form overlap-add + counts + mean write
// ------------------------------------------------------------------
__global__ void fold_kernel(const float* __restrict__ Y, const int* __restrict__ nnf,
                            const float* __restrict__ dsum, float* __restrict__ out) {
    int idx = blockIdx.x * 256 + threadIdx.x;
    if (idx < CC * TT) {
        int c = idx >> 13;          // /8192
        int t = idx & (TT - 1);
        float acc = 0.0f;
        int cnt = 0;
#pragma unroll
        for (int k = 0; k < PP; ++k) {
            int i = t - k;
            if (i >= 0 && i < NN) {
                acc += Y[c * TT + nnf[i] + k];
                cnt++;
            }
        }
        out[idx] = acc / (float)cnt;
    }
    if (idx == 0) out[CC * TT] = *dsum / (float)NN;
}

// ------------------------------------------------------------------
extern "C" void kernel_launch(void* const* d_in, const int* in_sizes, int n_in,
                              void* d_out, int out_size, void* d_ws, size_t ws_size,
                              hipStream_t stream) {
    const float* X = (const float*)d_in[0];
    const float* Y = (const float*)d_in[1];
    float* out = (float*)d_out;

    char* w = (char*)d_ws;
    float*              sx     = (float*)(w);                 // 32 KB
    float*              sy     = (float*)(w + (32u << 10));   // 32 KB
    unsigned*           colmin = (unsigned*)(w + (64u << 10)); // 32 KB
    int*                nnf    = (int*)(w + (96u << 10));     // 32 KB
    unsigned long long* packed = (unsigned long long*)(w + (128u << 10)); // 64 KB
    float*              dsum   = (float*)(w + (192u << 10));

    prep_kernel<<<(TT + 255) / 256, 256, 0, stream>>>(X, Y, sx, sy, colmin, packed, dsum);

    dim3 grid((NN + TJ - 1) / TJ, (NN + TI - 1) / TI);
    pass1_kernel<<<grid, 256, 0, stream>>>(X, Y, sx, sy, colmin);
    pass2_kernel<<<grid, 256, 0, stream>>>(X, Y, sx, sy, colmin, packed);

    finalize_kernel<<<(NN + 255) / 256, 256, 0, stream>>>(X, Y, sx, sy, packed, nnf, dsum);
    fold_kernel<<<(CC * TT + 255) / 256, 256, 0, stream>>>(Y, nnf, dsum, out);
}

// Round 2
// 516.894 us; speedup vs baseline: 4.4009x; 4.4009x over previous
//
#include <hip/hip_runtime.h>
#include <stdint.h>

// Problem constants (from reference)
#define TT 8192          // time length
#define CC 72            // channels
#define PP 7             // patch size
#define NN (TT - PP + 1) // 8186 patches
#define DD (CC * PP)     // 504 patch dim

#define TI 122           // output tile (both dims)
#define SG 128           // S grid = TI + PP - 1 = 128 exactly
#define SPAD 132         // padded S row stride (floats), 16B-aligned rows
#define NTILE ((NN + TI - 1) / TI)   // 68

#define STAGE_BYTES (CC * SG * 4)            // 36864 per buffer
#define SMEM_UNION  (2 * STAGE_BYTES)        // 73728 (Xs+Ys, aliased by S)

constexpr float INV_D = 1.0f / (float)DD;
constexpr float ALPHA_C = 0.01f;

// ------------------------------------------------------------------
// prep: patch norms sx/sy; init colmin (+inf bits), packed (~0), dsum
// ------------------------------------------------------------------
__global__ void prep_kernel(const float* __restrict__ X, const float* __restrict__ Y,
                            float* __restrict__ sx, float* __restrict__ sy,
                            unsigned* __restrict__ colmin,
                            unsigned long long* __restrict__ packed,
                            float* __restrict__ dsum) {
    int i = blockIdx.x * 256 + threadIdx.x;
    if (i == 0) *dsum = 0.0f;
    if (i < TT) { colmin[i] = 0x7f800000u; packed[i] = ~0ULL; }
    if (i < NN) {
        float ax = 0.0f, ay = 0.0f;
        for (int c = 0; c < CC; ++c) {
            const float* xr = X + c * TT + i;
            const float* yr = Y + c * TT + i;
#pragma unroll
            for (int k = 0; k < PP; ++k) {
                float v = xr[k]; ax += v * v;
                float w = yr[k]; ay += w * w;
            }
        }
        sx[i] = ax; sy[i] = ay;
    }
}

// ------------------------------------------------------------------
// shared tile engine: stage X/Y slices, build S = X^T Y (128x128, K=72)
// into LDS (aliased over stage), then per-thread 8x8 diagonal-sum dots.
// dot(a,b) = sum_{k=0..6} S[ri+a+k][rj+b+k]
// ------------------------------------------------------------------
__device__ __forceinline__ void tile_dots(const float* __restrict__ X,
                                          const float* __restrict__ Y,
                                          int i0, int j0, char* smem,
                                          float dot[8][8]) {
    float (*Xs)[SG]   = (float (*)[SG])smem;
    float (*Ys)[SG]   = (float (*)[SG])(smem + STAGE_BYTES);
    float (*Sl)[SPAD] = (float (*)[SPAD])smem;   // alias over Xs/Ys
    const int tid = threadIdx.x;

    // ---- stage (float2: i0/j0 always even since TI=122 is even) ----
    for (int idx = tid; idx < CC * SG / 2; idx += 256) {
        int c  = idx >> 6;           // /64
        int t2 = (idx & 63) * 2;
        int gx = i0 + t2, gy = j0 + t2;
        float2 xv, yv;
        if (gx + 1 < TT) xv = *(const float2*)(X + c * TT + gx);
        else { xv.x = X[c * TT + min(gx, TT - 1)]; xv.y = X[c * TT + min(gx + 1, TT - 1)]; }
        if (gy + 1 < TT) yv = *(const float2*)(Y + c * TT + gy);
        else { yv.x = Y[c * TT + min(gy, TT - 1)]; yv.y = Y[c * TT + min(gy + 1, TT - 1)]; }
        *(float2*)&Xs[c][t2] = xv;
        *(float2*)&Ys[c][t2] = yv;
    }
    __syncthreads();

    // ---- S compute: 16x16 units of 8x8, into registers ----
    const int su = tid >> 4, sv = tid & 15;
    float s[8][8];
#pragma unroll
    for (int a = 0; a < 8; ++a)
#pragma unroll
        for (int b = 0; b < 8; ++b) s[a][b] = 0.0f;

#pragma unroll 4
    for (int c = 0; c < CC; ++c) {
        float xv[8], yv[8];
        *(float4*)&xv[0] = *(const float4*)&Xs[c][su * 8];
        *(float4*)&xv[4] = *(const float4*)&Xs[c][su * 8 + 4];
        *(float4*)&yv[0] = *(const float4*)&Ys[c][sv * 8];
        *(float4*)&yv[4] = *(const float4*)&Ys[c][sv * 8 + 4];
#pragma unroll
        for (int a = 0; a < 8; ++a)
#pragma unroll
            for (int b = 0; b < 8; ++b)
                s[a][b] += xv[a] * yv[b];
    }
    __syncthreads();   // stage buffers dead; safe to overwrite with S

#pragma unroll
    for (int a = 0; a < 8; ++a) {
        *(float4*)&Sl[su * 8 + a][sv * 8]     = make_float4(s[a][0], s[a][1], s[a][2], s[a][3]);
        *(float4*)&Sl[su * 8 + a][sv * 8 + 4] = make_float4(s[a][4], s[a][5], s[a][6], s[a][7]);
    }
    __syncthreads();

    // ---- diagonal-band dot accumulation ----
    const int ri = (tid >> 4) * 8, rj = (tid & 15) * 8;
#pragma unroll
    for (int a = 0; a < 8; ++a)
#pragma unroll
        for (int b = 0; b < 8; ++b) dot[a][b] = 0.0f;

#pragma unroll
    for (int r = 0; r < 15; ++r) {
        // stray reads for edge threads stay inside smem[SMEM_UNION]; results masked
        float f[16];
        *(float4*)&f[0]  = *(const float4*)&Sl[ri + r][rj];
        *(float4*)&f[4]  = *(const float4*)&Sl[ri + r][rj + 4];
        *(float4*)&f[8]  = *(const float4*)&Sl[ri + r][rj + 8];
        *(float4*)&f[12] = *(const float4*)&Sl[ri + r][rj + 12];
#pragma unroll
        for (int a = 0; a < 8; ++a) {
            constexpr int dummy = 0; (void)dummy;
            const int k = r - a;
            if (k >= 0 && k < PP) {
#pragma unroll
                for (int b = 0; b < 8; ++b)
                    dot[a][b] += f[b + k];
            }
        }
    }
}

// ------------------------------------------------------------------
// pass1: column minima of dist; optional dist materialization
// ------------------------------------------------------------------
template<bool STORE>
__global__ __launch_bounds__(256) void pass1_k(
        const float* __restrict__ X, const float* __restrict__ Y,
        const float* __restrict__ sx, const float* __restrict__ sy,
        unsigned* __restrict__ colmin, float* __restrict__ distbuf) {
    __shared__ __align__(16) char smem[SMEM_UNION + 512];
    unsigned* cmin_s = (unsigned*)(smem + SMEM_UNION);

    const int i0 = blockIdx.y * TI;
    const int j0 = blockIdx.x * TI;
    const int tid = threadIdx.x;
    if (tid < 128) cmin_s[tid] = 0x7f800000u;

    float dot[8][8];
    tile_dots(X, Y, i0, j0, smem, dot);

    const int ri = (tid >> 4) * 8, rj = (tid & 15) * 8;
    const int gj0 = j0 + rj;

    bool bv[8]; float syv[8];
#pragma unroll
    for (int b = 0; b < 8; ++b) {
        int lj = rj + b, gj = gj0 + b;
        bv[b] = (lj < TI && gj < NN);
        syv[b] = bv[b] ? sy[gj] : 0.0f;
    }

    float cm[8];
#pragma unroll
    for (int b = 0; b < 8; ++b) cm[b] = __uint_as_float(0x7f800000u);

#pragma unroll
    for (int a = 0; a < 8; ++a) {
        int li = ri + a, gi = i0 + li;
        if (li >= TI || gi >= NN) continue;
        float sxi = sx[gi];
        float d8[8];
#pragma unroll
        for (int b = 0; b < 8; ++b)
            d8[b] = (sxi + syv[b] - 2.0f * dot[a][b]) * INV_D;
#pragma unroll
        for (int b = 0; b < 8; ++b)
            if (bv[b]) cm[b] = fminf(cm[b], d8[b]);
        if (STORE) {
            float* drow = distbuf + (size_t)gi * TT + gj0;
#pragma unroll
            for (int b = 0; b < 8; b += 2) {
                if (bv[b] && bv[b + 1]) *(float2*)&drow[b] = make_float2(d8[b], d8[b + 1]);
                else {
                    if (bv[b])     drow[b]     = d8[b];
                    if (bv[b + 1]) drow[b + 1] = d8[b + 1];
                }
            }
        }
    }
#pragma unroll
    for (int b = 0; b < 8; ++b)
        if (bv[b]) atomicMin(&cmin_s[rj + b], __float_as_uint(cm[b]));
    __syncthreads();
    if (tid < TI) {
        int gj = j0 + tid;
        if (gj < NN) atomicMin(&colmin[gj], cmin_s[tid]);
    }
}

// ------------------------------------------------------------------
// pass2 (recompute variant): row argmin of dist/(alpha+colmin[j])
// ------------------------------------------------------------------
__global__ __launch_bounds__(256) void pass2_k(
        const float* __restrict__ X, const float* __restrict__ Y,
        const float* __restrict__ sx, const float* __restrict__ sy,
        const unsigned* __restrict__ colmin,
        unsigned long long* __restrict__ packed) {
    __shared__ __align__(16) char smem[SMEM_UNION + 1024];
    unsigned long long* pmin_s = (unsigned long long*)(smem + SMEM_UNION);

    const int i0 = blockIdx.y * TI;
    const int j0 = blockIdx.x * TI;
    const int tid = threadIdx.x;
    if (tid < TI) pmin_s[tid] = ~0ULL;

    float dot[8][8];
    tile_dots(X, Y, i0, j0, smem, dot);

    const int ri = (tid >> 4) * 8, rj = (tid & 15) * 8;
    const int gj0 = j0 + rj;

    bool bv[8]; float syv[8], acm[8];
#pragma unroll
    for (int b = 0; b < 8; ++b) {
        int lj = rj + b, gj = gj0 + b;
        bv[b] = (lj < TI && gj < NN);
        syv[b] = bv[b] ? sy[gj] : 0.0f;
        acm[b] = bv[b] ? (ALPHA_C + __uint_as_float(colmin[gj])) : 1.0f;
    }

#pragma unroll
    for (int a = 0; a < 8; ++a) {
        int li = ri + a, gi = i0 + li;
        if (li >= TI || gi >= NN) continue;
        float sxi = sx[gi];
        unsigned long long best = ~0ULL;
#pragma unroll
        for (int b = 0; b < 8; ++b) {
            if (bv[b]) {
                float d  = (sxi + syv[b] - 2.0f * dot[a][b]) * INV_D;
                float nd = d / acm[b];
                unsigned long long pk =
                    ((unsigned long long)__float_as_uint(nd) << 32) | (unsigned)(gj0 + b);
                best = (pk < best) ? pk : best;
            }
        }
        atomicMin(&pmin_s[li], best);
    }
    __syncthreads();
    if (tid < TI) {
        int gi = i0 + tid;
        if (gi < NN) atomicMin(&packed[gi], pmin_s[tid]);
    }
}

// ------------------------------------------------------------------
// pass2 (load variant): stream materialized dist rows
// ------------------------------------------------------------------
__global__ __launch_bounds__(256) void pass2_load_k(
        const float* __restrict__ distbuf, const unsigned* __restrict__ colmin,
        unsigned long long* __restrict__ packed) {
    const int i = blockIdx.x;            // 0..NN-1
    const float* row = distbuf + (size_t)i * TT;
    const float* cmf = (const float*)colmin;

    unsigned long long best = ~0ULL;
    for (int jb = threadIdx.x * 4; jb < NN; jb += 1024) {
        float4 d4 = *(const float4*)(row + jb);
        float4 c4 = *(const float4*)(cmf + jb);
#pragma unroll
        for (int e = 0; e < 4; ++e) {
            int j = jb + e;
            float d  = (&d4.x)[e];
            float cm = (&c4.x)[e];
            if (j < NN) {
                float nd = d / (ALPHA_C + cm);
                unsigned long long pk =
                    ((unsigned long long)__float_as_uint(nd) << 32) | (unsigned)j;
                best = (pk < best) ? pk : best;
            }
        }
    }
#pragma unroll
    for (int off = 32; off > 0; off >>= 1) {
        unsigned long long o = __shfl_down(best, off, 64);
        best = (o < best) ? o : best;
    }
    __shared__ unsigned long long wb[4];
    int lane = threadIdx.x & 63, wid = threadIdx.x >> 6;
    if (lane == 0) wb[wid] = best;
    __syncthreads();
    if (threadIdx.x == 0) {
        unsigned long long b0 = wb[0];
        b0 = (wb[1] < b0) ? wb[1] : b0;
        b0 = (wb[2] < b0) ? wb[2] : b0;
        b0 = (wb[3] < b0) ? wb[3] : b0;
        packed[i] = b0;
    }
}

// ------------------------------------------------------------------
// finalize: nnf[i], dists[i] recompute, sum for mean
// ------------------------------------------------------------------
__global__ void finalize_kernel(const float* __restrict__ X, const float* __restrict__ Y,
                                const float* __restrict__ sx, const float* __restrict__ sy,
                                const unsigned long long* __restrict__ packed,
                                int* __restrict__ nnf, float* __restrict__ dsum) {
    int i = blockIdx.x * 256 + threadIdx.x;
    float dval = 0.0f;
    if (i < NN) {
        int j = (int)(packed[i] & 0xffffffffu);
        nnf[i] = j;
        float dot = 0.0f;
        for (int c = 0; c < CC; ++c) {
            const float* xr = X + c * TT + i;
            const float* yr = Y + c * TT + j;
#pragma unroll
            for (int k = 0; k < PP; ++k) dot += xr[k] * yr[k];
        }
        dval = (sx[i] + sy[j] - 2.0f * dot) * INV_D;
    }
    __shared__ float red[256];
    red[threadIdx.x] = dval;
    __syncthreads();
    for (int s = 128; s > 0; s >>= 1) {
        if (threadIdx.x < s) red[threadIdx.x] += red[threadIdx.x + s];
        __syncthreads();
    }
    if (threadIdx.x == 0) atomicAdd(dsum, red[0]);
}

// ------------------------------------------------------------------
// fold: gather-form overlap-add + counts + mean write
// ------------------------------------------------------------------
__global__ void fold_kernel(const float* __restrict__ Y, const int* __restrict__ nnf,
                            const float* __restrict__ dsum, float* __restrict__ out) {
    int idx = blockIdx.x * 256 + threadIdx.x;
    if (idx < CC * TT) {
        int c = idx >> 13;          // /8192
        int t = idx & (TT - 1);
        float acc = 0.0f;
        int cnt = 0;
#pragma unroll
        for (int k = 0; k < PP; ++k) {
            int i = t - k;
            if (i >= 0 && i < NN) {
                acc += Y[c * TT + nnf[i] + k];
                cnt++;
            }
        }
        out[idx] = acc / (float)cnt;
    }
    if (idx == 0) out[CC * TT] = *dsum / (float)NN;
}

// ------------------------------------------------------------------
extern "C" void kernel_launch(void* const* d_in, const int* in_sizes, int n_in,
                              void* d_out, int out_size, void* d_ws, size_t ws_size,
                              hipStream_t stream) {
    const float* X = (const float*)d_in[0];
    const float* Y = (const float*)d_in[1];
    float* out = (float*)d_out;

    char* w = (char*)d_ws;
    float*              sx     = (float*)(w);                  // 32 KB
    float*              sy     = (float*)(w + (32u << 10));    // 32 KB
    unsigned*           colmin = (unsigned*)(w + (64u << 10)); // 32 KB
    int*                nnf    = (int*)(w + (96u << 10));      // 32 KB
    unsigned long long* packed = (unsigned long long*)(w + (128u << 10)); // 64 KB
    float*              dsum   = (float*)(w + (192u << 10));
    float*              distbuf = (float*)(w + (1u << 20));    // optional 268 MB

    const size_t dist_bytes = (size_t)NN * TT * 4;             // 268,238,848
    const bool store = ws_size >= (1u << 20) + dist_bytes;

    prep_kernel<<<(TT + 255) / 256, 256, 0, stream>>>(X, Y, sx, sy, colmin, packed, dsum);

    dim3 grid(NTILE, NTILE);
    if (store) {
        pass1_k<true><<<grid, 256, 0, stream>>>(X, Y, sx, sy, colmin, distbuf);
        pass2_load_k<<<NN, 256, 0, stream>>>(distbuf, colmin, packed);
    } else {
        pass1_k<false><<<grid, 256, 0, stream>>>(X, Y, sx, sy, colmin, nullptr);
        pass2_k<<<grid, 256, 0, stream>>>(X, Y, sx, sy, colmin, packed);
    }

    finalize_kernel<<<(NN + 255) / 256, 256, 0, stream>>>(X, Y, sx, sy, packed, nnf, dsum);
    fold_kernel<<<(CC * TT + 255) / 256, 256, 0, stream>>>(Y, nnf, dsum, out);
}

// Round 4
// 454.567 us; speedup vs baseline: 5.0043x; 1.1371x over previous
//
#include <hip/hip_runtime.h>
#include <stdint.h>

// Problem constants (from reference)
#define TT 8192          // time length
#define CC 72            // channels
#define PP 7             // patch size
#define NN (TT - PP + 1) // 8186 patches
#define DD (CC * PP)     // 504 patch dim

#define TI 122           // output tile (both dims)
#define SG 128           // S grid = TI + PP - 1 = 128 exactly
#define SPAD 132         // padded S row stride (floats), 16B-aligned rows
#define NTILE ((NN + TI - 1) / TI)   // 68

#define STAGE_BYTES (CC * SG * 4)            // 36864 per buffer
#define SMEM_UNION  (2 * STAGE_BYTES)        // 73728 (Xs+Ys, aliased by S)

constexpr float INV_D = 1.0f / (float)DD;
constexpr float ALPHA_C = 0.01f;

// ------------------------------------------------------------------
// prep: patch norms sx/sy; init colmin (+inf bits), packed (~0), dsum
// ------------------------------------------------------------------
__global__ void prep_kernel(const float* __restrict__ X, const float* __restrict__ Y,
                            float* __restrict__ sx, float* __restrict__ sy,
                            unsigned* __restrict__ colmin,
                            unsigned long long* __restrict__ packed,
                            float* __restrict__ dsum) {
    int i = blockIdx.x * 256 + threadIdx.x;
    if (i == 0) *dsum = 0.0f;
    if (i < TT) { colmin[i] = 0x7f800000u; packed[i] = ~0ULL; }
    if (i < NN) {
        float ax = 0.0f, ay = 0.0f;
        for (int c = 0; c < CC; ++c) {
            const float* xr = X + c * TT + i;
            const float* yr = Y + c * TT + i;
#pragma unroll
            for (int k = 0; k < PP; ++k) {
                float v = xr[k]; ax += v * v;
                float w = yr[k]; ay += w * w;
            }
        }
        sx[i] = ax; sy[i] = ay;
    }
}

// ------------------------------------------------------------------
// shared tile engine: stage X/Y slices, build S = X^T Y (128x128, K=72)
// into LDS (aliased over stage, XOR-swizzled), then per-thread 8x8
// diagonal-sum dots: dot(a,b) = sum_{k=0..6} S[ri+a+k][rj+b+k]
//
// NOTE: every reordering here is bit-identical to the validated r2
// numerics (same per-accumulator summation order) — only layout moves.
//
// Bank-conflict design:
//  - S-phase operand reads: X rows contiguous-8 (broadcast-friendly);
//    Y cols split {4sv, 64+4sv} (full bank coverage across lanes).
//  - S store + diag read: col ^= ((row>>3)&3)<<2 — spreads the su-groups
//    (8 rows apart, 8*SPAD===0 mod 32 banks) across 4 bank-group offsets.
// ------------------------------------------------------------------
__device__ __forceinline__ void tile_dots(const float* __restrict__ X,
                                          const float* __restrict__ Y,
                                          int i0, int j0, char* smem,
                                          float dot[8][8]) {
    float (*Xs)[SG]   = (float (*)[SG])smem;
    float (*Ys)[SG]   = (float (*)[SG])(smem + STAGE_BYTES);
    float (*Sl)[SPAD] = (float (*)[SPAD])smem;   // alias over Xs/Ys
    const int tid = threadIdx.x;

    // ---- stage (float2: i0/j0 always even since TI=122 is even) ----
    for (int idx = tid; idx < CC * SG / 2; idx += 256) {
        int c  = idx >> 6;           // / (SG/2)
        int t2 = (idx & 63) * 2;
        int gx = i0 + t2, gy = j0 + t2;
        float2 xv, yv;
        if (gx + 1 < TT) xv = *(const float2*)(X + c * TT + gx);
        else { xv.x = X[c * TT + min(gx, TT - 1)]; xv.y = X[c * TT + min(gx + 1, TT - 1)]; }
        if (gy + 1 < TT) yv = *(const float2*)(Y + c * TT + gy);
        else { yv.x = Y[c * TT + min(gy, TT - 1)]; yv.y = Y[c * TT + min(gy + 1, TT - 1)]; }
        *(float2*)&Xs[c][t2] = xv;
        *(float2*)&Ys[c][t2] = yv;
    }
    __syncthreads();

    // ---- S compute: thread (su,sv) -> rows su*8..+7, cols {4sv..+3, 64+4sv..+3}
    const int su = tid >> 4, sv = tid & 15;
    float s[8][8];
#pragma unroll
    for (int a = 0; a < 8; ++a)
#pragma unroll
        for (int b = 0; b < 8; ++b) s[a][b] = 0.0f;

#pragma unroll 4
    for (int c = 0; c < CC; ++c) {
        float xv[8], yv[8];
        *(float4*)&xv[0] = *(const float4*)&Xs[c][su * 8];
        *(float4*)&xv[4] = *(const float4*)&Xs[c][su * 8 + 4];
        *(float4*)&yv[0] = *(const float4*)&Ys[c][sv * 4];
        *(float4*)&yv[4] = *(const float4*)&Ys[c][64 + sv * 4];
#pragma unroll
        for (int a = 0; a < 8; ++a)
#pragma unroll
            for (int b = 0; b < 8; ++b)
                s[a][b] += xv[a] * yv[b];
    }
    __syncthreads();   // stage buffers dead; safe to overwrite with S

#pragma unroll
    for (int a = 0; a < 8; ++a) {
        int row = su * 8 + a;
        int swz = ((row >> 3) & 3) << 2;
        *(float4*)&Sl[row][(sv * 4) ^ swz]      = make_float4(s[a][0], s[a][1], s[a][2], s[a][3]);
        *(float4*)&Sl[row][(64 + sv * 4) ^ swz] = make_float4(s[a][4], s[a][5], s[a][6], s[a][7]);
    }
    __syncthreads();

    // ---- diagonal-band dot accumulation (contiguous 8x8 per thread) ----
    const int ri = (tid >> 4) * 8, rj = (tid & 15) * 8;
#pragma unroll
    for (int a = 0; a < 8; ++a)
#pragma unroll
        for (int b = 0; b < 8; ++b) dot[a][b] = 0.0f;

#pragma unroll
    for (int r = 0; r < 14; ++r) {
        int row = ri + r;          // up to 133: stray reads stay inside smem, masked
        int swz = ((row >> 3) & 3) << 2;
        float f[14];
        *(float4*)&f[0]  = *(const float4*)&Sl[row][(rj)      ^ swz];
        *(float4*)&f[4]  = *(const float4*)&Sl[row][(rj + 4)  ^ swz];
        *(float4*)&f[8]  = *(const float4*)&Sl[row][(rj + 8)  ^ swz];
        *(float2*)&f[12] = *(const float2*)&Sl[row][(rj + 12) ^ swz];
#pragma unroll
        for (int a = 0; a < 8; ++a) {
            const int k = r - a;
            if (k >= 0 && k < PP) {
#pragma unroll
                for (int b = 0; b < 8; ++b)
                    dot[a][b] += f[b + k];
            }
        }
    }
}

// ------------------------------------------------------------------
// pass1: column minima of dist
// ------------------------------------------------------------------
__global__ __launch_bounds__(256) void pass1_k(
        const float* __restrict__ X, const float* __restrict__ Y,
        const float* __restrict__ sx, const float* __restrict__ sy,
        unsigned* __restrict__ colmin) {
    __shared__ __align__(16) char smem[SMEM_UNION + 1024];
    unsigned* cmin_s = (unsigned*)(smem + SMEM_UNION);

    const int i0 = blockIdx.y * TI;
    const int j0 = blockIdx.x * TI;
    const int tid = threadIdx.x;
    if (tid < 128) cmin_s[tid] = 0x7f800000u;

    float dot[8][8];
    tile_dots(X, Y, i0, j0, smem, dot);

    const int ri = (tid >> 4) * 8, rj = (tid & 15) * 8;
    const int gj0 = j0 + rj;

    bool bv[8]; float syv[8];
#pragma unroll
    for (int b = 0; b < 8; ++b) {
        int lj = rj + b, gj = gj0 + b;
        bv[b] = (lj < TI && gj < NN);
        syv[b] = bv[b] ? sy[gj] : 0.0f;
    }

    float cm[8];
#pragma unroll
    for (int b = 0; b < 8; ++b) cm[b] = __uint_as_float(0x7f800000u);

#pragma unroll
    for (int a = 0; a < 8; ++a) {
        int li = ri + a, gi = i0 + li;
        if (li >= TI || gi >= NN) continue;
        float sxi = sx[gi];
#pragma unroll
        for (int b = 0; b < 8; ++b) {
            float d = (sxi + syv[b] - 2.0f * dot[a][b]) * INV_D;
            if (bv[b]) cm[b] = fminf(cm[b], d);
        }
    }
#pragma unroll
    for (int b = 0; b < 8; ++b)
        if (bv[b]) atomicMin(&cmin_s[rj + b], __float_as_uint(cm[b]));
    __syncthreads();
    if (tid < TI) {
        int gj = j0 + tid;
        if (gj < NN) atomicMin(&colmin[gj], cmin_s[tid]);
    }
}

// ------------------------------------------------------------------
// pass2: row argmin of dist/(alpha+colmin[j]) — exact division as in
// the reference (and the validated round-2 kernel). packed (bits<<32)|j
// ------------------------------------------------------------------
__global__ __launch_bounds__(256) void pass2_k(
        const float* __restrict__ X, const float* __restrict__ Y,
        const float* __restrict__ sx, const float* __restrict__ sy,
        const unsigned* __restrict__ colmin,
        unsigned long long* __restrict__ packed) {
    __shared__ __align__(16) char smem[SMEM_UNION + 1024];
    unsigned long long* pmin_s = (unsigned long long*)(smem + SMEM_UNION);

    const int i0 = blockIdx.y * TI;
    const int j0 = blockIdx.x * TI;
    const int tid = threadIdx.x;
    if (tid < TI) pmin_s[tid] = ~0ULL;

    float dot[8][8];
    tile_dots(X, Y, i0, j0, smem, dot);

    const int ri = (tid >> 4) * 8, rj = (tid & 15) * 8;
    const int gj0 = j0 + rj;

    bool bv[8]; float syv[8], acm[8];
#pragma unroll
    for (int b = 0; b < 8; ++b) {
        int lj = rj + b, gj = gj0 + b;
        bv[b] = (lj < TI && gj < NN);
        syv[b] = bv[b] ? sy[gj] : 0.0f;
        acm[b] = bv[b] ? (ALPHA_C + __uint_as_float(colmin[gj])) : 1.0f;
    }

#pragma unroll
    for (int a = 0; a < 8; ++a) {
        int li = ri + a, gi = i0 + li;
        if (li >= TI || gi >= NN) continue;
        float sxi = sx[gi];
        unsigned long long best = ~0ULL;
#pragma unroll
        for (int b = 0; b < 8; ++b) {
            if (bv[b]) {
                float d  = (sxi + syv[b] - 2.0f * dot[a][b]) * INV_D;
                float nd = d / acm[b];   // exact division — do NOT replace with reciprocal
                unsigned long long pk =
                    ((unsigned long long)__float_as_uint(nd) << 32) | (unsigned)(gj0 + b);
                best = (pk < best) ? pk : best;
            }
        }
        atomicMin(&pmin_s[li], best);
    }
    __syncthreads();
    if (tid < TI) {
        int gi = i0 + tid;
        if (gi < NN) atomicMin(&packed[gi], pmin_s[tid]);
    }
}

// ------------------------------------------------------------------
// finalize: nnf[i], dists[i] recompute, sum for mean
// ------------------------------------------------------------------
__global__ void finalize_kernel(const float* __restrict__ X, const float* __restrict__ Y,
                                const float* __restrict__ sx, const float* __restrict__ sy,
                                const unsigned long long* __restrict__ packed,
                                int* __restrict__ nnf, float* __restrict__ dsum) {
    int i = blockIdx.x * 256 + threadIdx.x;
    float dval = 0.0f;
    if (i < NN) {
        int j = (int)(packed[i] & 0xffffffffu);
        nnf[i] = j;
        float dot = 0.0f;
        for (int c = 0; c < CC; ++c) {
            const float* xr = X + c * TT + i;
            const float* yr = Y + c * TT + j;
#pragma unroll
            for (int k = 0; k < PP; ++k) dot += xr[k] * yr[k];
        }
        dval = (sx[i] + sy[j] - 2.0f * dot) * INV_D;
    }
    __shared__ float red[256];
    red[threadIdx.x] = dval;
    __syncthreads();
    for (int s = 128; s > 0; s >>= 1) {
        if (threadIdx.x < s) red[threadIdx.x] += red[threadIdx.x + s];
        __syncthreads();
    }
    if (threadIdx.x == 0) atomicAdd(dsum, red[0]);
}

// ------------------------------------------------------------------
// fold: gather-form overlap-add + counts + mean write
// ------------------------------------------------------------------
__global__ void fold_kernel(const float* __restrict__ Y, const int* __restrict__ nnf,
                            const float* __restrict__ dsum, float* __restrict__ out) {
    int idx = blockIdx.x * 256 + threadIdx.x;
    if (idx < CC * TT) {
        int c = idx >> 13;          // /8192
        int t = idx & (TT - 1);
        float acc = 0.0f;
        int cnt = 0;
#pragma unroll
        for (int k = 0; k < PP; ++k) {
            int i = t - k;
            if (i >= 0 && i < NN) {
                acc += Y[c * TT + nnf[i] + k];
                cnt++;
            }
        }
        out[idx] = acc / (float)cnt;
    }
    if (idx == 0) out[CC * TT] = *dsum / (float)NN;
}

// ------------------------------------------------------------------
extern "C" void kernel_launch(void* const* d_in, const int* in_sizes, int n_in,
                              void* d_out, int out_size, void* d_ws, size_t ws_size,
                              hipStream_t stream) {
    const float* X = (const float*)d_in[0];
    const float* Y = (const float*)d_in[1];
    float* out = (float*)d_out;

    char* w = (char*)d_ws;
    float*              sx     = (float*)(w);                  // 32 KB
    float*              sy     = (float*)(w + (32u << 10));    // 32 KB
    unsigned*           colmin = (unsigned*)(w + (64u << 10)); // 32 KB
    int*                nnf    = (int*)(w + (96u << 10));      // 32 KB
    unsigned long long* packed = (unsigned long long*)(w + (128u << 10)); // 64 KB
    float*              dsum   = (float*)(w + (192u << 10));

    prep_kernel<<<(TT + 255) / 256, 256, 0, stream>>>(X, Y, sx, sy, colmin, packed, dsum);

    dim3 grid(NTILE, NTILE);
    pass1_k<<<grid, 256, 0, stream>>>(X, Y, sx, sy, colmin);
    pass2_k<<<grid, 256, 0, stream>>>(X, Y, sx, sy, colmin, packed);

    finalize_kernel<<<(NN + 255) / 256, 256, 0, stream>>>(X, Y, sx, sy, packed, nnf, dsum);
    fold_kernel<<<(CC * TT + 255) / 256, 256, 0, stream>>>(Y, nnf, dsum, out);
}

// Round 5
// 426.576 us; speedup vs baseline: 5.3327x; 1.0656x over previous
//
#include <hip/hip_runtime.h>
#include <stdint.h>

// Problem constants (from reference)
#define TT 8192          // time length
#define CC 72            // channels
#define PP 7             // patch size
#define NN (TT - PP + 1) // 8186 patches
#define DD (CC * PP)     // 504 patch dim

#define TI 122           // output tile (both dims)
#define SG 128           // S grid = TI + PP - 1 = 128 exactly
#define SPAD 132         // padded S row stride (floats), 16B-aligned rows
#define NTILE ((NN + TI - 1) / TI)   // 68

#define STAGE_BYTES (CC * SG * 4)            // 36864 per buffer
#define SMEM_UNION  (2 * STAGE_BYTES)        // 73728 (Xs+Ys, aliased by S)

// tail scratch block: 192 KiB total, placed at end of ws so dist can use the front
#define TAIL_BYTES 196608

constexpr float INV_D = 1.0f / (float)DD;
constexpr float ALPHA_C = 0.01f;

// ------------------------------------------------------------------
// prep: patch norms sx/sy; init colmin (+inf bits), packed (~0), dsum
// ------------------------------------------------------------------
__global__ void prep_kernel(const float* __restrict__ X, const float* __restrict__ Y,
                            float* __restrict__ sx, float* __restrict__ sy,
                            unsigned* __restrict__ colmin,
                            unsigned long long* __restrict__ packed,
                            float* __restrict__ dsum) {
    int i = blockIdx.x * 256 + threadIdx.x;
    if (i == 0) *dsum = 0.0f;
    if (i < TT) { colmin[i] = 0x7f800000u; packed[i] = ~0ULL; }
    if (i < NN) {
        float ax = 0.0f, ay = 0.0f;
        for (int c = 0; c < CC; ++c) {
            const float* xr = X + c * TT + i;
            const float* yr = Y + c * TT + i;
#pragma unroll
            for (int k = 0; k < PP; ++k) {
                float v = xr[k]; ax += v * v;
                float w = yr[k]; ay += w * w;
            }
        }
        sx[i] = ax; sy[i] = ay;
    }
}

// ------------------------------------------------------------------
// shared tile engine (validated r4 numerics — bit-identical everywhere):
// stage X/Y slices, build S = X^T Y (128x128, K=72) into LDS (aliased
// over stage, XOR-swizzled), then per-thread 8x8 diagonal-sum dots:
// dot(a,b) = sum_{k=0..6} S[ri+a+k][rj+b+k]
// ------------------------------------------------------------------
__device__ __forceinline__ void tile_dots(const float* __restrict__ X,
                                          const float* __restrict__ Y,
                                          int i0, int j0, char* smem,
                                          float dot[8][8]) {
    float (*Xs)[SG]   = (float (*)[SG])smem;
    float (*Ys)[SG]   = (float (*)[SG])(smem + STAGE_BYTES);
    float (*Sl)[SPAD] = (float (*)[SPAD])smem;   // alias over Xs/Ys
    const int tid = threadIdx.x;

    // ---- stage (float2: i0/j0 always even since TI=122 is even) ----
    for (int idx = tid; idx < CC * SG / 2; idx += 256) {
        int c  = idx >> 6;           // / (SG/2)
        int t2 = (idx & 63) * 2;
        int gx = i0 + t2, gy = j0 + t2;
        float2 xv, yv;
        if (gx + 1 < TT) xv = *(const float2*)(X + c * TT + gx);
        else { xv.x = X[c * TT + min(gx, TT - 1)]; xv.y = X[c * TT + min(gx + 1, TT - 1)]; }
        if (gy + 1 < TT) yv = *(const float2*)(Y + c * TT + gy);
        else { yv.x = Y[c * TT + min(gy, TT - 1)]; yv.y = Y[c * TT + min(gy + 1, TT - 1)]; }
        *(float2*)&Xs[c][t2] = xv;
        *(float2*)&Ys[c][t2] = yv;
    }
    __syncthreads();

    // ---- S compute: thread (su,sv) -> rows su*8..+7, cols {4sv..+3, 64+4sv..+3}
    const int su = tid >> 4, sv = tid & 15;
    float s[8][8];
#pragma unroll
    for (int a = 0; a < 8; ++a)
#pragma unroll
        for (int b = 0; b < 8; ++b) s[a][b] = 0.0f;

#pragma unroll 4
    for (int c = 0; c < CC; ++c) {
        float xv[8], yv[8];
        *(float4*)&xv[0] = *(const float4*)&Xs[c][su * 8];
        *(float4*)&xv[4] = *(const float4*)&Xs[c][su * 8 + 4];
        *(float4*)&yv[0] = *(const float4*)&Ys[c][sv * 4];
        *(float4*)&yv[4] = *(const float4*)&Ys[c][64 + sv * 4];
#pragma unroll
        for (int a = 0; a < 8; ++a)
#pragma unroll
            for (int b = 0; b < 8; ++b)
                s[a][b] += xv[a] * yv[b];
    }
    __syncthreads();   // stage buffers dead; safe to overwrite with S

#pragma unroll
    for (int a = 0; a < 8; ++a) {
        int row = su * 8 + a;
        int swz = ((row >> 3) & 3) << 2;
        *(float4*)&Sl[row][(sv * 4) ^ swz]      = make_float4(s[a][0], s[a][1], s[a][2], s[a][3]);
        *(float4*)&Sl[row][(64 + sv * 4) ^ swz] = make_float4(s[a][4], s[a][5], s[a][6], s[a][7]);
    }
    __syncthreads();

    // ---- diagonal-band dot accumulation (contiguous 8x8 per thread) ----
    const int ri = (tid >> 4) * 8, rj = (tid & 15) * 8;
#pragma unroll
    for (int a = 0; a < 8; ++a)
#pragma unroll
        for (int b = 0; b < 8; ++b) dot[a][b] = 0.0f;

#pragma unroll
    for (int r = 0; r < 14; ++r) {
        int row = ri + r;          // up to 133: stray reads stay inside smem, masked
        int swz = ((row >> 3) & 3) << 2;
        float f[14];
        *(float4*)&f[0]  = *(const float4*)&Sl[row][(rj)      ^ swz];
        *(float4*)&f[4]  = *(const float4*)&Sl[row][(rj + 4)  ^ swz];
        *(float4*)&f[8]  = *(const float4*)&Sl[row][(rj + 8)  ^ swz];
        *(float2*)&f[12] = *(const float2*)&Sl[row][(rj + 12) ^ swz];
#pragma unroll
        for (int a = 0; a < 8; ++a) {
            const int k = r - a;
            if (k >= 0 && k < PP) {
#pragma unroll
                for (int b = 0; b < 8; ++b)
                    dot[a][b] += f[b + k];
            }
        }
    }
}

// ------------------------------------------------------------------
// pass1: column minima of dist; tiles with blockIdx.y < storeTiles also
// write their dist rows (bit-exact d values) to distbuf[row][col].
// ------------------------------------------------------------------
__global__ __launch_bounds__(256) void pass1_k(
        const float* __restrict__ X, const float* __restrict__ Y,
        const float* __restrict__ sx, const float* __restrict__ sy,
        unsigned* __restrict__ colmin,
        float* __restrict__ distbuf, int storeTiles) {
    __shared__ __align__(16) char smem[SMEM_UNION + 1024];
    unsigned* cmin_s = (unsigned*)(smem + SMEM_UNION);

    const int i0 = blockIdx.y * TI;
    const int j0 = blockIdx.x * TI;
    const int tid = threadIdx.x;
    const bool store = ((int)blockIdx.y < storeTiles);   // block-uniform
    if (tid < 128) cmin_s[tid] = 0x7f800000u;

    float dot[8][8];
    tile_dots(X, Y, i0, j0, smem, dot);

    const int ri = (tid >> 4) * 8, rj = (tid & 15) * 8;
    const int gj0 = j0 + rj;

    bool bv[8]; float syv[8];
#pragma unroll
    for (int b = 0; b < 8; ++b) {
        int lj = rj + b, gj = gj0 + b;
        bv[b] = (lj < TI && gj < NN);
        syv[b] = bv[b] ? sy[gj] : 0.0f;
    }

    float cm[8];
#pragma unroll
    for (int b = 0; b < 8; ++b) cm[b] = __uint_as_float(0x7f800000u);

#pragma unroll
    for (int a = 0; a < 8; ++a) {
        int li = ri + a, gi = i0 + li;
        if (li >= TI || gi >= NN) continue;
        float sxi = sx[gi];
        float d8[8];
#pragma unroll
        for (int b = 0; b < 8; ++b) {
            d8[b] = (sxi + syv[b] - 2.0f * dot[a][b]) * INV_D;
            if (bv[b]) cm[b] = fminf(cm[b], d8[b]);
        }
        if (store) {
            float* drow = distbuf + (size_t)gi * TT + gj0;
#pragma unroll
            for (int b = 0; b < 8; b += 2) {   // gj0+b is 8B-aligned (all even)
                if (bv[b] && bv[b + 1]) *(float2*)&drow[b] = make_float2(d8[b], d8[b + 1]);
                else {
                    if (bv[b])     drow[b]     = d8[b];
                    if (bv[b + 1]) drow[b + 1] = d8[b + 1];
                }
            }
        }
    }
#pragma unroll
    for (int b = 0; b < 8; ++b)
        if (bv[b]) atomicMin(&cmin_s[rj + b], __float_as_uint(cm[b]));
    __syncthreads();
    if (tid < TI) {
        int gj = j0 + tid;
        if (gj < NN) atomicMin(&colmin[gj], cmin_s[tid]);
    }
}

// ------------------------------------------------------------------
// pass2a: stream stored dist rows; exact same nd = d/(alpha+cm) and
// (bits<<32)|j packing as the validated recompute path. One block/row.
// ------------------------------------------------------------------
__global__ __launch_bounds__(256) void pass2_stream_k(
        const float* __restrict__ distbuf, const unsigned* __restrict__ colmin,
        unsigned long long* __restrict__ packed) {
    const int i = blockIdx.x;
    const float* row = distbuf + (size_t)i * TT;
    const float* cmf = (const float*)colmin;   // bit pattern of nonneg floats

    unsigned long long best = ~0ULL;
    for (int jb = threadIdx.x * 4; jb < NN; jb += 1024) {
        float4 d4 = *(const float4*)(row + jb);
        float4 c4 = *(const float4*)(cmf + jb);
#pragma unroll
        for (int e = 0; e < 4; ++e) {
            int j = jb + e;
            if (j < NN) {
                float acm = ALPHA_C + (&c4.x)[e];
                float nd  = (&d4.x)[e] / acm;    // exact division, matches pass2_k
                unsigned long long pk =
                    ((unsigned long long)__float_as_uint(nd) << 32) | (unsigned)j;
                best = (pk < best) ? pk : best;
            }
        }
    }
#pragma unroll
    for (int off = 32; off > 0; off >>= 1) {
        unsigned long long o = __shfl_down(best, off, 64);
        best = (o < best) ? o : best;
    }
    __shared__ unsigned long long wb[4];
    int lane = threadIdx.x & 63, wid = threadIdx.x >> 6;
    if (lane == 0) wb[wid] = best;
    __syncthreads();
    if (threadIdx.x == 0) {
        unsigned long long b0 = wb[0];
        b0 = (wb[1] < b0) ? wb[1] : b0;
        b0 = (wb[2] < b0) ? wb[2] : b0;
        b0 = (wb[3] < b0) ? wb[3] : b0;
        packed[i] = b0;   // this kernel owns row i entirely
    }
}

// ------------------------------------------------------------------
// pass2b: recompute variant for unstored i-tiles (validated r4 kernel
// with an i-tile offset). nd via exact division.
// ------------------------------------------------------------------
__global__ __launch_bounds__(256) void pass2_k(
        const float* __restrict__ X, const float* __restrict__ Y,
        const float* __restrict__ sx, const float* __restrict__ sy,
        const unsigned* __restrict__ colmin,
        unsigned long long* __restrict__ packed, int itile_ofs) {
    __shared__ __align__(16) char smem[SMEM_UNION + 1024];
    unsigned long long* pmin_s = (unsigned long long*)(smem + SMEM_UNION);

    const int i0 = (itile_ofs + blockIdx.y) * TI;
    const int j0 = blockIdx.x * TI;
    const int tid = threadIdx.x;
    if (tid < TI) pmin_s[tid] = ~0ULL;

    float dot[8][8];
    tile_dots(X, Y, i0, j0, smem, dot);

    const int ri = (tid >> 4) * 8, rj = (tid & 15) * 8;
    const int gj0 = j0 + rj;

    bool bv[8]; float syv[8], acm[8];
#pragma unroll
    for (int b = 0; b < 8; ++b) {
        int lj = rj + b, gj = gj0 + b;
        bv[b] = (lj < TI && gj < NN);
        syv[b] = bv[b] ? sy[gj] : 0.0f;
        acm[b] = bv[b] ? (ALPHA_C + __uint_as_float(colmin[gj])) : 1.0f;
    }

#pragma unroll
    for (int a = 0; a < 8; ++a) {
        int li = ri + a, gi = i0 + li;
        if (li >= TI || gi >= NN) continue;
        float sxi = sx[gi];
        unsigned long long best = ~0ULL;
#pragma unroll
        for (int b = 0; b < 8; ++b) {
            if (bv[b]) {
                float d  = (sxi + syv[b] - 2.0f * dot[a][b]) * INV_D;
                float nd = d / acm[b];   // exact division — do NOT replace with reciprocal
                unsigned long long pk =
                    ((unsigned long long)__float_as_uint(nd) << 32) | (unsigned)(gj0 + b);
                best = (pk < best) ? pk : best;
            }
        }
        atomicMin(&pmin_s[li], best);
    }
    __syncthreads();
    if (tid < TI) {
        int gi = i0 + tid;
        if (gi < NN) atomicMin(&packed[gi], pmin_s[tid]);
    }
}

// ------------------------------------------------------------------
// finalize: nnf[i], dists[i] recompute, sum for mean
// ------------------------------------------------------------------
__global__ void finalize_kernel(const float* __restrict__ X, const float* __restrict__ Y,
                                const float* __restrict__ sx, const float* __restrict__ sy,
                                const unsigned long long* __restrict__ packed,
                                int* __restrict__ nnf, float* __restrict__ dsum) {
    int i = blockIdx.x * 256 + threadIdx.x;
    float dval = 0.0f;
    if (i < NN) {
        int j = (int)(packed[i] & 0xffffffffu);
        nnf[i] = j;
        float dot = 0.0f;
        for (int c = 0; c < CC; ++c) {
            const float* xr = X + c * TT + i;
            const float* yr = Y + c * TT + j;
#pragma unroll
            for (int k = 0; k < PP; ++k) dot += xr[k] * yr[k];
        }
        dval = (sx[i] + sy[j] - 2.0f * dot) * INV_D;
    }
    __shared__ float red[256];
    red[threadIdx.x] = dval;
    __syncthreads();
    for (int s = 128; s > 0; s >>= 1) {
        if (threadIdx.x < s) red[threadIdx.x] += red[threadIdx.x + s];
        __syncthreads();
    }
    if (threadIdx.x == 0) atomicAdd(dsum, red[0]);
}

// ------------------------------------------------------------------
// fold: gather-form overlap-add + counts + mean write
// ------------------------------------------------------------------
__global__ void fold_kernel(const float* __restrict__ Y, const int* __restrict__ nnf,
                            const float* __restrict__ dsum, float* __restrict__ out) {
    int idx = blockIdx.x * 256 + threadIdx.x;
    if (idx < CC * TT) {
        int c = idx >> 13;          // /8192
        int t = idx & (TT - 1);
        float acc = 0.0f;
        int cnt = 0;
#pragma unroll
        for (int k = 0; k < PP; ++k) {
            int i = t - k;
            if (i >= 0 && i < NN) {
                acc += Y[c * TT + nnf[i] + k];
                cnt++;
            }
        }
        out[idx] = acc / (float)cnt;
    }
    if (idx == 0) out[CC * TT] = *dsum / (float)NN;
}

// ------------------------------------------------------------------
extern "C" void kernel_launch(void* const* d_in, const int* in_sizes, int n_in,
                              void* d_out, int out_size, void* d_ws, size_t ws_size,
                              hipStream_t stream) {
    const float* X = (const float*)d_in[0];
    const float* Y = (const float*)d_in[1];
    float* out = (float*)d_out;

    // ---- ws partition: dist rows at front, 192 KiB scratch at tail ----
    // tail base aligned down to 32 KiB so full 32 KB dist rows fit below it.
    char* w = (char*)d_ws;
    size_t base = 0;
    if (ws_size > TAIL_BYTES) base = ((ws_size - TAIL_BYTES) / 32768) * 32768;
    // tail layout (fits in 192 KiB):
    unsigned long long* packed = (unsigned long long*)(w + base);            // 65536
    unsigned*           colmin = (unsigned*)(w + base + 65536);              // 32768
    float*              sx     = (float*)(w + base + 98304);                 // 32744
    float*              sy     = (float*)(w + base + 131072);                // 32744
    int*                nnf    = (int*)(w + base + 163840);                  // 32744
    float*              dsum   = (float*)(w + base + 196600);                // 4
    float*              distbuf = (float*)w;                                 // up to base bytes

    // how many whole i-tiles of dist rows fit in [0, base)?
    const long storeRows = (long)(base / ((size_t)TT * 4));
    int storeTiles = 0;
    for (int nT = 1; nT <= NTILE; ++nT) {
        long need = (long)nT * TI; if (need > NN) need = NN;
        if (need <= storeRows) storeTiles = nT; else break;
    }
    const int SR = (storeTiles * TI < NN) ? storeTiles * TI : NN;  // stored row count

    prep_kernel<<<(TT + 255) / 256, 256, 0, stream>>>(X, Y, sx, sy, colmin, packed, dsum);

    dim3 grid(NTILE, NTILE);
    pass1_k<<<grid, 256, 0, stream>>>(X, Y, sx, sy, colmin, distbuf, storeTiles);

    if (SR > 0)
        pass2_stream_k<<<SR, 256, 0, stream>>>(distbuf, colmin, packed);
    if (storeTiles < NTILE) {
        dim3 grid2(NTILE, NTILE - storeTiles);
        pass2_k<<<grid2, 256, 0, stream>>>(X, Y, sx, sy, colmin, packed, storeTiles);
    }

    finalize_kernel<<<(NN + 255) / 256, 256, 0, stream>>>(X, Y, sx, sy, packed, nnf, dsum);
    fold_kernel<<<(CC * TT + 255) / 256, 256, 0, stream>>>(Y, nnf, dsum, out);
}

// Round 6
// 327.047 us; speedup vs baseline: 6.9556x; 1.3043x over previous
//
#include <hip/hip_runtime.h>
#include <stdint.h>

// Problem constants (from reference)
#define TT 8192          // time length
#define CC 72            // channels
#define PP 7             // patch size
#define NN (TT - PP + 1) // 8186 patches
#define DD (CC * PP)     // 504 patch dim

#define TI 122           // output tile (both dims)
#define SG 128           // S grid = TI + PP - 1 = 128 exactly
#define SPAD 132         // padded S row stride (floats), 16B-aligned rows
#define NTILE ((NN + TI - 1) / TI)   // 68

#define STAGE_BYTES (CC * SG * 4)            // 36864 per buffer
#define SMEM_UNION  (2 * STAGE_BYTES)        // 73728 (Xs+Ys, aliased by S)

// tail scratch block: 192 KiB total, placed at end of ws so dist can use the front
#define TAIL_BYTES 196608

constexpr float INV_D = 1.0f / (float)DD;
constexpr float ALPHA_C = 0.01f;

// ------------------------------------------------------------------
// prep: patch norms sx/sy; init colmin (+inf bits), packed (~0), dsum
// ------------------------------------------------------------------
__global__ void prep_kernel(const float* __restrict__ X, const float* __restrict__ Y,
                            float* __restrict__ sx, float* __restrict__ sy,
                            unsigned* __restrict__ colmin,
                            unsigned long long* __restrict__ packed,
                            float* __restrict__ dsum) {
    int i = blockIdx.x * 256 + threadIdx.x;
    if (i == 0) *dsum = 0.0f;
    if (i < TT) { colmin[i] = 0x7f800000u; packed[i] = ~0ULL; }
    if (i < NN) {
        float ax = 0.0f, ay = 0.0f;
        for (int c = 0; c < CC; ++c) {
            const float* xr = X + c * TT + i;
            const float* yr = Y + c * TT + i;
#pragma unroll
            for (int k = 0; k < PP; ++k) {
                float v = xr[k]; ax += v * v;
                float w = yr[k]; ay += w * w;
            }
        }
        sx[i] = ax; sy[i] = ay;
    }
}

// ------------------------------------------------------------------
// shared tile engine (validated numerics — bit-identical everywhere):
// stage X/Y slices, build S = X^T Y (128x128, K=72) into LDS (aliased
// over stage, XOR-swizzled), then per-thread 8x8 diagonal-sum dots:
// dot(a,b) = sum_{k=0..6} S[ri+a+k][rj+b+k]
// ------------------------------------------------------------------
__device__ __forceinline__ void tile_dots(const float* __restrict__ X,
                                          const float* __restrict__ Y,
                                          int i0, int j0, char* smem,
                                          float dot[8][8]) {
    float (*Xs)[SG]   = (float (*)[SG])smem;
    float (*Ys)[SG]   = (float (*)[SG])(smem + STAGE_BYTES);
    float (*Sl)[SPAD] = (float (*)[SPAD])smem;   // alias over Xs/Ys
    const int tid = threadIdx.x;

    // ---- stage (float2: i0/j0 always even since TI=122 is even) ----
    for (int idx = tid; idx < CC * SG / 2; idx += 256) {
        int c  = idx >> 6;           // / (SG/2)
        int t2 = (idx & 63) * 2;
        int gx = i0 + t2, gy = j0 + t2;
        float2 xv, yv;
        if (gx + 1 < TT) xv = *(const float2*)(X + c * TT + gx);
        else { xv.x = X[c * TT + min(gx, TT - 1)]; xv.y = X[c * TT + min(gx + 1, TT - 1)]; }
        if (gy + 1 < TT) yv = *(const float2*)(Y + c * TT + gy);
        else { yv.x = Y[c * TT + min(gy, TT - 1)]; yv.y = Y[c * TT + min(gy + 1, TT - 1)]; }
        *(float2*)&Xs[c][t2] = xv;
        *(float2*)&Ys[c][t2] = yv;
    }
    __syncthreads();

    // ---- S compute: thread (su,sv) -> rows su*8..+7, cols {4sv..+3, 64+4sv..+3}
    const int su = tid >> 4, sv = tid & 15;
    float s[8][8];
#pragma unroll
    for (int a = 0; a < 8; ++a)
#pragma unroll
        for (int b = 0; b < 8; ++b) s[a][b] = 0.0f;

#pragma unroll 4
    for (int c = 0; c < CC; ++c) {
        float xv[8], yv[8];
        *(float4*)&xv[0] = *(const float4*)&Xs[c][su * 8];
        *(float4*)&xv[4] = *(const float4*)&Xs[c][su * 8 + 4];
        *(float4*)&yv[0] = *(const float4*)&Ys[c][sv * 4];
        *(float4*)&yv[4] = *(const float4*)&Ys[c][64 + sv * 4];
#pragma unroll
        for (int a = 0; a < 8; ++a)
#pragma unroll
            for (int b = 0; b < 8; ++b)
                s[a][b] += xv[a] * yv[b];
    }
    __syncthreads();   // stage buffers dead; safe to overwrite with S

#pragma unroll
    for (int a = 0; a < 8; ++a) {
        int row = su * 8 + a;
        int swz = ((row >> 3) & 3) << 2;
        *(float4*)&Sl[row][(sv * 4) ^ swz]      = make_float4(s[a][0], s[a][1], s[a][2], s[a][3]);
        *(float4*)&Sl[row][(64 + sv * 4) ^ swz] = make_float4(s[a][4], s[a][5], s[a][6], s[a][7]);
    }
    __syncthreads();

    // ---- diagonal-band dot accumulation (contiguous 8x8 per thread) ----
    const int ri = (tid >> 4) * 8, rj = (tid & 15) * 8;
#pragma unroll
    for (int a = 0; a < 8; ++a)
#pragma unroll
        for (int b = 0; b < 8; ++b) dot[a][b] = 0.0f;

#pragma unroll
    for (int r = 0; r < 14; ++r) {
        int row = ri + r;          // up to 133: stray reads stay inside smem, masked
        int swz = ((row >> 3) & 3) << 2;
        float f[14];
        *(float4*)&f[0]  = *(const float4*)&Sl[row][(rj)      ^ swz];
        *(float4*)&f[4]  = *(const float4*)&Sl[row][(rj + 4)  ^ swz];
        *(float4*)&f[8]  = *(const float4*)&Sl[row][(rj + 8)  ^ swz];
        *(float2*)&f[12] = *(const float2*)&Sl[row][(rj + 12) ^ swz];
#pragma unroll
        for (int a = 0; a < 8; ++a) {
            const int k = r - a;
            if (k >= 0 && k < PP) {
#pragma unroll
                for (int b = 0; b < 8; ++b)
                    dot[a][b] += f[b + k];
            }
        }
    }
}

// ------------------------------------------------------------------
// pass1: column minima of dist; tiles with blockIdx.y < storeTiles also
// write their dist rows (bit-exact d values) to distbuf[row][col].
// Store fast path: wide stores, uniform branches (alignment is
// block-uniform since gj0%4 == (122*bx)%4; fullCols is thread-uniform).
// ------------------------------------------------------------------
__global__ __launch_bounds__(256) void pass1_k(
        const float* __restrict__ X, const float* __restrict__ Y,
        const float* __restrict__ sx, const float* __restrict__ sy,
        unsigned* __restrict__ colmin,
        float* __restrict__ distbuf, int storeTiles) {
    __shared__ __align__(16) char smem[SMEM_UNION + 1024];
    unsigned* cmin_s = (unsigned*)(smem + SMEM_UNION);

    const int i0 = blockIdx.y * TI;
    const int j0 = blockIdx.x * TI;
    const int tid = threadIdx.x;
    const bool store = ((int)blockIdx.y < storeTiles);   // block-uniform
    if (tid < 128) cmin_s[tid] = 0x7f800000u;

    float dot[8][8];
    tile_dots(X, Y, i0, j0, smem, dot);

    const int ri = (tid >> 4) * 8, rj = (tid & 15) * 8;
    const int gj0 = j0 + rj;

    bool bv[8]; float syv[8];
#pragma unroll
    for (int b = 0; b < 8; ++b) {
        int lj = rj + b, gj = gj0 + b;
        bv[b] = (lj < TI && gj < NN);
        syv[b] = bv[b] ? sy[gj] : 0.0f;
    }
    const bool fullCols = (rj + 7 < TI) && (gj0 + 7 < NN);  // thread-uniform
    const bool al16 = ((gj0 & 3) == 0);                     // block-uniform

    float cm[8];
#pragma unroll
    for (int b = 0; b < 8; ++b) cm[b] = __uint_as_float(0x7f800000u);

#pragma unroll
    for (int a = 0; a < 8; ++a) {
        int li = ri + a, gi = i0 + li;
        if (li >= TI || gi >= NN) continue;
        float sxi = sx[gi];
        float d8[8];
#pragma unroll
        for (int b = 0; b < 8; ++b) {
            d8[b] = (sxi + syv[b] - 2.0f * dot[a][b]) * INV_D;
            if (bv[b]) cm[b] = fminf(cm[b], d8[b]);
        }
        if (store) {
            float* drow = distbuf + (size_t)gi * TT + gj0;
            if (fullCols) {
                if (al16) {
                    *(float4*)&drow[0] = make_float4(d8[0], d8[1], d8[2], d8[3]);
                    *(float4*)&drow[4] = make_float4(d8[4], d8[5], d8[6], d8[7]);
                } else {   // gj0 % 4 == 2: 8B / 16B / 8B, all naturally aligned
                    *(float2*)&drow[0] = make_float2(d8[0], d8[1]);
                    *(float4*)&drow[2] = make_float4(d8[2], d8[3], d8[4], d8[5]);
                    *(float2*)&drow[6] = make_float2(d8[6], d8[7]);
                }
            } else {
#pragma unroll
                for (int b = 0; b < 8; ++b)
                    if (bv[b]) drow[b] = d8[b];
            }
        }
    }
#pragma unroll
    for (int b = 0; b < 8; ++b)
        if (bv[b]) atomicMin(&cmin_s[rj + b], __float_as_uint(cm[b]));
    __syncthreads();
    if (tid < TI) {
        int gj = j0 + tid;
        if (gj < NN) atomicMin(&colmin[gj], cmin_s[tid]);
    }
}

// ------------------------------------------------------------------
// pass2 stream: one block per stored row. Same nd = d/(alpha+cm) and
// (bits<<32)|j packing as the validated recompute path (first-occurrence
// tie-break via u64 min). FULL: writes nnf[i] + dists[i] directly;
// else writes packed[i] for the hybrid path.
// ------------------------------------------------------------------
template<bool FULL>
__global__ __launch_bounds__(256) void pass2_stream_k(
        const float* __restrict__ distbuf, const unsigned* __restrict__ colmin,
        unsigned long long* __restrict__ packed,
        int* __restrict__ nnf, float* __restrict__ dists) {
    const int i = blockIdx.x;
    const float* row = distbuf + (size_t)i * TT;
    const float* cmf = (const float*)colmin;   // bit pattern of nonneg floats

    unsigned long long best = ~0ULL;
    for (int jb = threadIdx.x * 8; jb < NN; jb += 2048) {
        float4 d4a = *(const float4*)(row + jb);
        float4 d4b = *(const float4*)(row + jb + 4);
        float4 c4a = *(const float4*)(cmf + jb);
        float4 c4b = *(const float4*)(cmf + jb + 4);
#pragma unroll
        for (int e = 0; e < 8; ++e) {
            int j = jb + e;
            if (j < NN) {
                float d   = (e < 4) ? (&d4a.x)[e] : (&d4b.x)[e - 4];
                float cmv = (e < 4) ? (&c4a.x)[e] : (&c4b.x)[e - 4];
                float nd  = d / (ALPHA_C + cmv);    // exact division, matches pass2_k
                unsigned long long pk =
                    ((unsigned long long)__float_as_uint(nd) << 32) | (unsigned)j;
                best = (pk < best) ? pk : best;
            }
        }
    }
#pragma unroll
    for (int off = 32; off > 0; off >>= 1) {
        unsigned long long o = __shfl_down(best, off, 64);
        best = (o < best) ? o : best;
    }
    __shared__ unsigned long long wb[4];
    int lane = threadIdx.x & 63, wid = threadIdx.x >> 6;
    if (lane == 0) wb[wid] = best;
    __syncthreads();
    if (threadIdx.x == 0) {
        unsigned long long b0 = wb[0];
        b0 = (wb[1] < b0) ? wb[1] : b0;
        b0 = (wb[2] < b0) ? wb[2] : b0;
        b0 = (wb[3] < b0) ? wb[3] : b0;
        if (FULL) {
            int j = (int)(b0 & 0xffffffffu);
            nnf[i]   = j;
            dists[i] = row[j];      // bit-exact stored dist value
        } else {
            packed[i] = b0;         // this kernel owns row i entirely
        }
    }
}

// ------------------------------------------------------------------
// meansum: single-block reduce of dists[0..NN) -> *dsum
// ------------------------------------------------------------------
__global__ __launch_bounds__(256) void meansum_kernel(
        const float* __restrict__ dists, float* __restrict__ dsum) {
    float s = 0.0f;
    for (int i = threadIdx.x; i < NN; i += 256) s += dists[i];
    __shared__ float red[256];
    red[threadIdx.x] = s;
    __syncthreads();
    for (int st = 128; st > 0; st >>= 1) {
        if (threadIdx.x < st) red[threadIdx.x] += red[threadIdx.x + st];
        __syncthreads();
    }
    if (threadIdx.x == 0) *dsum = red[0];
}

// ------------------------------------------------------------------
// pass2b: recompute variant for unstored i-tiles (validated kernel with
// an i-tile offset). nd via exact division.
// ------------------------------------------------------------------
__global__ __launch_bounds__(256) void pass2_k(
        const float* __restrict__ X, const float* __restrict__ Y,
        const float* __restrict__ sx, const float* __restrict__ sy,
        const unsigned* __restrict__ colmin,
        unsigned long long* __restrict__ packed, int itile_ofs) {
    __shared__ __align__(16) char smem[SMEM_UNION + 1024];
    unsigned long long* pmin_s = (unsigned long long*)(smem + SMEM_UNION);

    const int i0 = (itile_ofs + blockIdx.y) * TI;
    const int j0 = blockIdx.x * TI;
    const int tid = threadIdx.x;
    if (tid < TI) pmin_s[tid] = ~0ULL;

    float dot[8][8];
    tile_dots(X, Y, i0, j0, smem, dot);

    const int ri = (tid >> 4) * 8, rj = (tid & 15) * 8;
    const int gj0 = j0 + rj;

    bool bv[8]; float syv[8], acm[8];
#pragma unroll
    for (int b = 0; b < 8; ++b) {
        int lj = rj + b, gj = gj0 + b;
        bv[b] = (lj < TI && gj < NN);
        syv[b] = bv[b] ? sy[gj] : 0.0f;
        acm[b] = bv[b] ? (ALPHA_C + __uint_as_float(colmin[gj])) : 1.0f;
    }

#pragma unroll
    for (int a = 0; a < 8; ++a) {
        int li = ri + a, gi = i0 + li;
        if (li >= TI || gi >= NN) continue;
        float sxi = sx[gi];
        unsigned long long best = ~0ULL;
#pragma unroll
        for (int b = 0; b < 8; ++b) {
            if (bv[b]) {
                float d  = (sxi + syv[b] - 2.0f * dot[a][b]) * INV_D;
                float nd = d / acm[b];   // exact division — do NOT replace with reciprocal
                unsigned long long pk =
                    ((unsigned long long)__float_as_uint(nd) << 32) | (unsigned)(gj0 + b);
                best = (pk < best) ? pk : best;
            }
        }
        atomicMin(&pmin_s[li], best);
    }
    __syncthreads();
    if (tid < TI) {
        int gi = i0 + tid;
        if (gi < NN) atomicMin(&packed[gi], pmin_s[tid]);
    }
}

// ------------------------------------------------------------------
// finalize (hybrid path only): nnf[i], dists[i] recompute, sum for mean
// ------------------------------------------------------------------
__global__ void finalize_kernel(const float* __restrict__ X, const float* __restrict__ Y,
                                const float* __restrict__ sx, const float* __restrict__ sy,
                                const unsigned long long* __restrict__ packed,
                                int* __restrict__ nnf, float* __restrict__ dsum) {
    int i = blockIdx.x * 256 + threadIdx.x;
    float dval = 0.0f;
    if (i < NN) {
        int j = (int)(packed[i] & 0xffffffffu);
        nnf[i] = j;
        float dot = 0.0f;
        for (int c = 0; c < CC; ++c) {
            const float* xr = X + c * TT + i;
            const float* yr = Y + c * TT + j;
#pragma unroll
            for (int k = 0; k < PP; ++k) dot += xr[k] * yr[k];
        }
        dval = (sx[i] + sy[j] - 2.0f * dot) * INV_D;
    }
    __shared__ float red[256];
    red[threadIdx.x] = dval;
    __syncthreads();
    for (int s = 128; s > 0; s >>= 1) {
        if (threadIdx.x < s) red[threadIdx.x] += red[threadIdx.x + s];
        __syncthreads();
    }
    if (threadIdx.x == 0) atomicAdd(dsum, red[0]);
}

// ------------------------------------------------------------------
// fold: gather-form overlap-add + counts + mean write
// ------------------------------------------------------------------
__global__ void fold_kernel(const float* __restrict__ Y, const int* __restrict__ nnf,
                            const float* __restrict__ dsum, float* __restrict__ out) {
    int idx = blockIdx.x * 256 + threadIdx.x;
    if (idx < CC * TT) {
        int c = idx >> 13;          // /8192
        int t = idx & (TT - 1);
        float acc = 0.0f;
        int cnt = 0;
#pragma unroll
        for (int k = 0; k < PP; ++k) {
            int i = t - k;
            if (i >= 0 && i < NN) {
                acc += Y[c * TT + nnf[i] + k];
                cnt++;
            }
        }
        out[idx] = acc / (float)cnt;
    }
    if (idx == 0) out[CC * TT] = *dsum / (float)NN;
}

// ------------------------------------------------------------------
extern "C" void kernel_launch(void* const* d_in, const int* in_sizes, int n_in,
                              void* d_out, int out_size, void* d_ws, size_t ws_size,
                              hipStream_t stream) {
    const float* X = (const float*)d_in[0];
    const float* Y = (const float*)d_in[1];
    float* out = (float*)d_out;

    // ---- ws partition: dist rows at front, 192 KiB scratch at tail ----
    // tail base aligned down to 32 KiB so full 32 KB dist rows fit below it.
    char* w = (char*)d_ws;
    size_t base = 0;
    if (ws_size > TAIL_BYTES) base = ((ws_size - TAIL_BYTES) / 32768) * 32768;
    // tail layout (fits in 192 KiB). dists aliases packed: packed is used
    // only on the hybrid path, dists only on the full-store path.
    unsigned long long* packed = (unsigned long long*)(w + base);            // 65536
    float*              dists  = (float*)(w + base);                         // alias
    unsigned*           colmin = (unsigned*)(w + base + 65536);              // 32768
    float*              sx     = (float*)(w + base + 98304);                 // 32744
    float*              sy     = (float*)(w + base + 131072);                // 32744
    int*                nnf    = (int*)(w + base + 163840);                  // 32744
    float*              dsum   = (float*)(w + base + 196600);                // 4
    float*              distbuf = (float*)w;                                 // up to base bytes

    // how many whole i-tiles of dist rows fit in [0, base)?
    const long storeRows = (long)(base / ((size_t)TT * 4));
    int storeTiles = 0;
    for (int nT = 1; nT <= NTILE; ++nT) {
        long need = (long)nT * TI; if (need > NN) need = NN;
        if (need <= storeRows) storeTiles = nT; else break;
    }
    const int SR = (storeTiles * TI < NN) ? storeTiles * TI : NN;  // stored row count
    const bool full = (storeTiles >= NTILE);

    prep_kernel<<<(TT + 255) / 256, 256, 0, stream>>>(X, Y, sx, sy, colmin, packed, dsum);

    dim3 grid(NTILE, NTILE);
    pass1_k<<<grid, 256, 0, stream>>>(X, Y, sx, sy, colmin, distbuf, storeTiles);

    if (full) {
        pass2_stream_k<true><<<NN, 256, 0, stream>>>(distbuf, colmin, packed, nnf, dists);
        meansum_kernel<<<1, 256, 0, stream>>>(dists, dsum);
    } else {
        if (SR > 0)
            pass2_stream_k<false><<<SR, 256, 0, stream>>>(distbuf, colmin, packed, nnf, dists);
        if (storeTiles < NTILE) {
            dim3 grid2(NTILE, NTILE - storeTiles);
            pass2_k<<<grid2, 256, 0, stream>>>(X, Y, sx, sy, colmin, packed, storeTiles);
        }
        finalize_kernel<<<(NN + 255) / 256, 256, 0, stream>>>(X, Y, sx, sy, packed, nnf, dsum);
    }
    fold_kernel<<<(CC * TT + 255) / 256, 256, 0, stream>>>(Y, nnf, dsum, out);
}